// Round 12
// baseline (339.630 us; speedup 1.0000x reference)
//
#include <hip/hip_runtime.h>

#define IN_DIM 200
#define HID    256
#define OUT_D  64
#define RREL   2
#define NEG_SLOPE 0.2f
#define NNODE  50000
#define MPAD   50048          // ceil(50000/128)*128 — staging-safe row pad

typedef __attribute__((ext_vector_type(8))) short bf16x8;
typedef __attribute__((ext_vector_type(4))) float f32x4;
typedef __attribute__((ext_vector_type(2))) float f32x2;
typedef __attribute__((ext_vector_type(4))) unsigned int u32x4;

__device__ __forceinline__ float bf2f(unsigned short u) {
    union { unsigned int i; float f; } v; v.i = ((unsigned int)u) << 16; return v.f;
}
__device__ __forceinline__ unsigned short f2bf(float f) {
    union { float f; unsigned int i; } v; v.f = f;
    unsigned int u = v.i;
    return (unsigned short)((u + 0x7FFFu + ((u >> 16) & 1u)) >> 16);   // RNE
}
__device__ __forceinline__ float elu(float v) { return v > 0.f ? v : (__expf(v) - 1.0f); }

// ---------------------------------------------------------------------------
// Merged prep kernel: all weight/feature converts + wqk + buffer zeroing.
// ---------------------------------------------------------------------------
__device__ __forceinline__ void wt_cvt_body(
    const float* __restrict__ in, unsigned short* __restrict__ out,
    int Kreal, int Nreal, int Kpad, int Npad, int nb, long long idx)
{
    long long total = (long long)nb * Npad * Kpad;
    if (idx >= total) return;
    int kk = (int)(idx % Kpad);
    long long t = idx / Kpad;
    int nrow = (int)(t % Npad);
    int z = (int)(t / Npad);
    float f = (kk < Kreal && nrow < Nreal) ? in[((long long)z * Kreal + kk) * Nreal + nrow] : 0.f;
    out[idx] = f2bf(f);
}

#define PB_FEAT   12512                    // feat_cvt: MPAD*64/256
#define PB_WST    (PB_FEAT + 512)          // wt_cvt_stack
#define PB_W2T    (PB_WST + 128)           // w2 -> w2t
#define PB_DW1    (PB_W2T + 64)            // dW1 -> dW1t
#define PB_DW2    (PB_DW1 + 256)           // dW2 -> dW2t
#define PB_WQK    (PB_DW2 + 128)           // wqk
#define PB_DEG    (PB_WQK + 391)           // deg2 zero
#define PB_QK2    (PB_DEG + 391)           // qnb2/knb2 zero

__global__ __launch_bounds__(256) void prep_all(
    const float* __restrict__ features, const float* __restrict__ w1,
    const float* __restrict__ w2, const float* __restrict__ dW1,
    const float* __restrict__ dW2, const float* __restrict__ q1,
    const float* __restrict__ k1,
    unsigned short* __restrict__ A1, unsigned short* __restrict__ wst,
    unsigned short* __restrict__ w2t, unsigned short* __restrict__ dW1t,
    unsigned short* __restrict__ dW2t, float* __restrict__ wqv,
    float* __restrict__ wkv, int* __restrict__ deg2,
    float* __restrict__ qnb2, float* __restrict__ knb2, int n2)
{
    const int b = blockIdx.x;
    const int tid = threadIdx.x;

    if (b < PB_FEAT) {
        long long idx = (long long)b * 256 + tid;
        int row = (int)(idx >> 6);
        int c4  = ((int)idx & 63) << 2;
        if (row >= MPAD) return;
        unsigned short v[4];
        #pragma unroll
        for (int i = 0; i < 4; ++i) {
            int c = c4 + i;
            float f = (row < NNODE && c < IN_DIM) ? features[(long long)row * IN_DIM + c] : 0.f;
            v[i] = f2bf(f);
        }
        *(ushort4*)(A1 + (long long)row * 256 + c4) = make_ushort4(v[0], v[1], v[2], v[3]);
    } else if (b < PB_WST) {
        int idx = (b - PB_FEAT) * 256 + tid;
        if (idx >= 2 * 256 * 256) return;
        int kk = idx & 255;
        int c  = (idx >> 8) & 255;
        int z  = idx >> 16;
        float f = (kk < IN_DIM) ? w1[((long long)z * IN_DIM + kk) * 256 + c] : 0.f;
        wst[(long long)c * 512 + z * 256 + kk] = f2bf(f);
    } else if (b < PB_W2T) {
        wt_cvt_body(w2, w2t, HID, OUT_D, 256, 64, RREL, (long long)(b - PB_WST) * 256 + tid);
    } else if (b < PB_DW1) {
        wt_cvt_body(dW1, dW1t, OUT_D, HID, 64, 256, 1, (long long)(b - PB_W2T) * 256 + tid);
    } else if (b < PB_DW2) {
        wt_cvt_body(dW2, dW2t, HID, IN_DIM, 256, 256, 1, (long long)(b - PB_DW1) * 256 + tid);
    } else if (b < PB_WQK) {
        int wv = (((b - PB_DW2) << 8) + tid) >> 6;
        int lane = tid & 63;
        if (wv >= 512) return;
        int r = wv >> 8, kk = wv & 255;
        float sq = 0.f, sk = 0.f;
        if (kk < IN_DIM) {                   // wave-uniform (kk from wave id)
            const float* row = w1 + ((long long)(r * IN_DIM + kk)) * 256;
            float4 wv4 = *(const float4*)(row + lane * 4);
            float4 qv4 = *(const float4*)(q1 + lane * 4);
            float4 kv4 = *(const float4*)(k1 + lane * 4);
            sq = wv4.x * qv4.x + wv4.y * qv4.y + wv4.z * qv4.z + wv4.w * qv4.w;
            sk = wv4.x * kv4.x + wv4.y * kv4.y + wv4.z * kv4.z + wv4.w * kv4.w;
            #pragma unroll
            for (int off = 32; off; off >>= 1) {
                sq += __shfl_xor(sq, off);
                sk += __shfl_xor(sk, off);
            }
        }
        if (lane == 0) { wqv[r * 256 + kk] = sq; wkv[r * 256 + kk] = sk; }
    } else if (b < PB_DEG) {
        int i = (b - PB_WQK) * 256 + tid;
        if (i < n2) deg2[i] = 0;
    } else if (b < PB_QK2) {
        int i = (b - PB_DEG) * 256 + tid;
        if (i < n2) { qnb2[i] = 0.f; knb2[i] = 0.f; }
    }
}

// qn/kn for layer 1 from padded features: one wave per node, both relations.
__global__ __launch_bounds__(256) void qk_feat(
    const unsigned short* __restrict__ A1, const float* __restrict__ wqv,
    const float* __restrict__ wkv, float* __restrict__ qn, float* __restrict__ kn, int n)
{
    int wv = ((blockIdx.x << 8) + threadIdx.x) >> 6;
    int lane = threadIdx.x & 63;
    if (wv >= n) return;
    ushort4 v = *(const ushort4*)(A1 + (long long)wv * 256 + lane * 4);
    float x0 = bf2f(v.x), x1 = bf2f(v.y), x2 = bf2f(v.z), x3 = bf2f(v.w);
    float4 q0v = *(const float4*)(wqv + lane * 4);
    float4 k0v = *(const float4*)(wkv + lane * 4);
    float4 q1v = *(const float4*)(wqv + 256 + lane * 4);
    float4 k1v = *(const float4*)(wkv + 256 + lane * 4);
    float sq0 = x0 * q0v.x + x1 * q0v.y + x2 * q0v.z + x3 * q0v.w;
    float sk0 = x0 * k0v.x + x1 * k0v.y + x2 * k0v.z + x3 * k0v.w;
    float sq1 = x0 * q1v.x + x1 * q1v.y + x2 * q1v.z + x3 * q1v.w;
    float sk1 = x0 * k1v.x + x1 * k1v.y + x2 * k1v.z + x3 * k1v.w;
    #pragma unroll
    for (int off = 32; off; off >>= 1) {
        sq0 += __shfl_xor(sq0, off);
        sk0 += __shfl_xor(sk0, off);
        sq1 += __shfl_xor(sq1, off);
        sk1 += __shfl_xor(sk1, off);
    }
    if (lane == 0) {
        qn[wv] = sq0; qn[n + wv] = sq1;
        kn[wv] = sk0; kn[n + wv] = sk1;
    }
}

// ---------------------------------------------------------------------------
// bf16 MFMA GEMM (optional fused ELU / fused q,k row-dots via atomicAdd).
// ---------------------------------------------------------------------------
template<bool OUT_BF16, bool DO_ELU, bool FUSE_QK>
__global__ __launch_bounds__(256) void gemm_mfma(
    const unsigned short* __restrict__ A,
    const unsigned short* __restrict__ Bt,
    const float* __restrict__ bias,
    void* __restrict__ Cout,
    const float* __restrict__ qvec, const float* __restrict__ kvec,
    float* __restrict__ qn_out, float* __restrict__ kn_out,
    int M, int Nn, int Kp, int Npad,
    long long strideC)
{
    __shared__ __align__(16) char lds[49152];   // 2 x (A 16KB + B 8KB)
    const int tid  = threadIdx.x;
    const int lane = tid & 63;
    const int w    = tid >> 6;
    const int m0   = blockIdx.x * 128;
    const int n0   = blockIdx.y * 64;
    const int z    = blockIdx.z;

    const char* Ab = (const char*)A;
    const char* Bb = (const char*)(Bt + (long long)z * Npad * Kp);
    const int rs = Kp * 2;

    f32x4 acc[2][4];
    #pragma unroll
    for (int i = 0; i < 2; ++i)
        #pragma unroll
        for (int j = 0; j < 4; ++j) acc[i][j] = (f32x4){0.f, 0.f, 0.f, 0.f};

    const int KT = Kp >> 6;

    auto stage = [&](int buf, int kt) {
        char* lA = lds + buf * 24576;
        char* lB = lA + 16384;
        #pragma unroll
        for (int i = 0; i < 4; ++i) {
            int g = i * 256 + tid;
            int row = g >> 3, c = g & 7;
            const char* src = Ab + (long long)(m0 + row) * rs + kt * 128 + ((c ^ (row & 7)) << 4);
            __builtin_amdgcn_global_load_lds((const __attribute__((address_space(1))) void*)src,
                                             (__attribute__((address_space(3))) void*)(lA + g * 16),
                                             16, 0, 0);
        }
        #pragma unroll
        for (int i = 0; i < 2; ++i) {
            int g = i * 256 + tid;
            int row = g >> 3, c = g & 7;
            const char* src = Bb + (long long)(n0 + row) * rs + kt * 128 + ((c ^ (row & 7)) << 4);
            __builtin_amdgcn_global_load_lds((const __attribute__((address_space(1))) void*)src,
                                             (__attribute__((address_space(3))) void*)(lB + g * 16),
                                             16, 0, 0);
        }
    };

    stage(0, 0);
    int cur = 0;
    for (int kt = 0; kt < KT; ++kt) {
        __syncthreads();
        if (kt + 1 < KT) stage(cur ^ 1, kt + 1);
        const char* lA = lds + cur * 24576;
        const char* lB = lA + 16384;
        #pragma unroll
        for (int ks = 0; ks < 2; ++ks) {
            const int kg = ks * 4 + (lane >> 4);
            bf16x8 a[2], b[4];
            #pragma unroll
            for (int mi = 0; mi < 2; ++mi) {
                int row = w * 32 + mi * 16 + (lane & 15);
                a[mi] = *(const bf16x8*)(lA + row * 128 + ((kg ^ (row & 7)) << 4));
            }
            #pragma unroll
            for (int nj = 0; nj < 4; ++nj) {
                int row = nj * 16 + (lane & 15);
                b[nj] = *(const bf16x8*)(lB + row * 128 + ((kg ^ (row & 7)) << 4));
            }
            #pragma unroll
            for (int mi = 0; mi < 2; ++mi)
                #pragma unroll
                for (int nj = 0; nj < 4; ++nj)
                    acc[mi][nj] = __builtin_amdgcn_mfma_f32_16x16x32_bf16(a[mi], b[nj], acc[mi][nj], 0, 0, 0);
        }
        cur ^= 1;
    }

    // epilogue: C/D layout col=lane&15, row=(lane>>4)*4+r
    const int colb = n0 + (lane & 15);
    #pragma unroll
    for (int mi = 0; mi < 2; ++mi) {
        #pragma unroll
        for (int nj = 0; nj < 4; ++nj) {
            int col = colb + nj * 16;
            if (col >= Nn) continue;
            float badd = bias ? bias[col] : 0.f;
            #pragma unroll
            for (int r = 0; r < 4; ++r) {
                int rowm = m0 + w * 32 + mi * 16 + ((lane >> 4) << 2) + r;
                if (rowm >= M) continue;
                float v = acc[mi][nj][r] + badd;
                if (DO_ELU) v = v > 0.f ? v : (__expf(v) - 1.0f);
                if (OUT_BF16)
                    ((unsigned short*)Cout)[strideC * z + (long long)rowm * Nn + col] = f2bf(v);
                else
                    ((float*)Cout)[strideC * z + (long long)rowm * Nn + col] = v;
            }
        }
    }

    if (FUSE_QK) {
        float qv[4], kv[4];
        #pragma unroll
        for (int nj = 0; nj < 4; ++nj) {
            int col = colb + nj * 16;
            bool ok = col < Nn;
            qv[nj] = ok ? qvec[col] : 0.f;
            kv[nj] = ok ? kvec[col] : 0.f;
        }
        #pragma unroll
        for (int mi = 0; mi < 2; ++mi) {
            #pragma unroll
            for (int r = 0; r < 4; ++r) {
                float sq = 0.f, sk = 0.f;
                #pragma unroll
                for (int nj = 0; nj < 4; ++nj) {
                    sq = fmaf(acc[mi][nj][r], qv[nj], sq);
                    sk = fmaf(acc[mi][nj][r], kv[nj], sk);
                }
                #pragma unroll
                for (int off = 1; off < 16; off <<= 1) {   // full-wave, uniform
                    sq += __shfl_xor(sq, off);
                    sk += __shfl_xor(sk, off);
                }
                if ((lane & 15) == 0) {
                    int rowm = m0 + w * 32 + mi * 16 + ((lane >> 4) << 2) + r;
                    if (rowm < M) {
                        atomicAdd(qn_out + (long long)z * M + rowm, sq);
                        atomicAdd(kn_out + (long long)z * M + rowm, sk);
                    }
                }
            }
        }
    }
}

// ---------------------------------------------------------------------------
// CSR build — relation-segmented: counters indexed 2*dst + etype
// ---------------------------------------------------------------------------
__global__ void count_kernel(const int* __restrict__ dst, const int* __restrict__ etype,
                             int* __restrict__ deg2, int E)
{
    int e = blockIdx.x * 256 + threadIdx.x;
    if (e < E) atomicAdd(&deg2[(dst[e] << 1) | etype[e]], 1);
}

__global__ __launch_bounds__(256) void scan_blocksum(
    const int* __restrict__ deg, int* __restrict__ bsum, int n)
{
    __shared__ int red[256];
    int i = blockIdx.x * 256 + threadIdx.x;
    int v = (i < n) ? deg[i] : 0;
    red[threadIdx.x] = v;
    __syncthreads();
    #pragma unroll
    for (int off = 128; off; off >>= 1) {
        if (threadIdx.x < off) red[threadIdx.x] += red[threadIdx.x + off];
        __syncthreads();
    }
    if (threadIdx.x == 0) bsum[blockIdx.x] = red[0];
}

// exclusive scan of <=512 block sums (single block, 512 threads)
__global__ __launch_bounds__(512) void scan_bsum(int* __restrict__ bsum, int nb)
{
    __shared__ int buf[512];
    const int t = threadIdx.x;
    int v = (t < nb) ? bsum[t] : 0;
    buf[t] = v;
    __syncthreads();
    #pragma unroll
    for (int off = 1; off < 512; off <<= 1) {
        int u = (t >= off) ? buf[t - off] : 0;
        __syncthreads();
        buf[t] += u;
        __syncthreads();
    }
    if (t < nb) bsum[t] = buf[t] - v;   // exclusive
}

__global__ __launch_bounds__(256) void scan_final(
    const int* __restrict__ deg, const int* __restrict__ bsum,
    int* __restrict__ row_ptr, int* __restrict__ cursor, int n)
{
    __shared__ int buf[256];
    const int t = threadIdx.x;
    const int i = blockIdx.x * 256 + t;
    int v = (i < n) ? deg[i] : 0;
    buf[t] = v;
    __syncthreads();
    #pragma unroll
    for (int off = 1; off < 256; off <<= 1) {
        int u = (t >= off) ? buf[t - off] : 0;
        __syncthreads();
        buf[t] += u;
        __syncthreads();
    }
    int excl = bsum[blockIdx.x] + buf[t] - v;
    if (i < n) { row_ptr[i] = excl; cursor[i] = excl; }
    if (i == n - 1) row_ptr[n] = excl + v;
}

__global__ void scatter_kernel(const int* __restrict__ dst, const int* __restrict__ src,
                               const int* __restrict__ etype, int* __restrict__ cursor2,
                               int* __restrict__ epk, int E)
{
    int e = blockIdx.x * 256 + threadIdx.x;
    if (e < E) {
        int p = atomicAdd(&cursor2[(dst[e] << 1) | etype[e]], 1);
        epk[p] = src[e];                 // plain src; relation implicit in segment
    }
}

// ---------------------------------------------------------------------------
// Layer-1 aggregation into z. Fast path (union degree <= 64, ~always):
// single-pass softmax, 8 gathers issued before any fma (4 k-steps x 2 segs),
// __launch_bounds__(256,4) -> 64 VGPR so the loads actually stay in flight.
// Slow path: 3-pass chunked. Uniform shfls only; masked slots -> row 0, w=0.
// ---------------------------------------------------------------------------
__global__ __launch_bounds__(256, 4) void aggregate_z(
    const unsigned short* __restrict__ A1,   // [MPAD][256] bf16
    const float* __restrict__ qn,            // [2][n]
    const float* __restrict__ kn,            // [2][n]
    const int* __restrict__ row_ptr2,        // [2n+1]
    const int* __restrict__ epk,             // [E] src
    unsigned short* __restrict__ z,          // [MPAD][512] bf16
    int n)
{
    const int wv   = ((blockIdx.x << 8) + threadIdx.x) >> 6;
    const int lane = threadIdx.x & 63;
    if (wv >= n) return;
    const int d = wv;
    const int start = row_ptr2[2 * d];
    const int mid   = row_ptr2[2 * d + 1];
    const int end   = row_ptr2[2 * d + 2];
    const int cnt = end - start;
    const int c0  = mid - start;
    const float q0 = qn[d];
    const float q1 = qn[n + d];
    const int slot = lane >> 5;
    const int hl   = lane & 31;

    auto fma8v = [](f32x2 acc[4], float w, const u32x4& r) {
        #pragma unroll
        for (int t2 = 0; t2 < 4; ++t2) {
            f32x2 x;
            x.x = __uint_as_float(r[t2] << 16);
            x.y = __uint_as_float(r[t2] & 0xFFFF0000u);
            acc[t2] += w * x;               // -> v_pk_fma_f32
        }
    };
    auto fma8s = [](float acc[8], float w, const u32x4& r) {
        #pragma unroll
        for (int t2 = 0; t2 < 4; ++t2) {
            unsigned dw = r[t2];
            acc[2 * t2]     = fmaf(w, __uint_as_float(dw << 16),         acc[2 * t2]);
            acc[2 * t2 + 1] = fmaf(w, __uint_as_float(dw & 0xFFFF0000u), acc[2 * t2 + 1]);
        }
    };

    if (cnt <= 64) {
        // ---- fast path ----
        int pv = 0; float a = -INFINITY;
        if (lane < cnt) {
            pv = epk[start + lane];
            bool r1 = lane >= c0;
            a = (r1 ? q1 : q0) + kn[(r1 ? n : 0) + pv];
            a = a > 0.f ? a : NEG_SLOPE * a;
        }
        float mx = a;
        #pragma unroll
        for (int off = 32; off; off >>= 1) mx = fmaxf(mx, __shfl_xor(mx, off));
        float ev = (lane < cnt) ? __expf(a - mx) : 0.f;
        float se = ev;
        #pragma unroll
        for (int off = 32; off; off >>= 1) se += __shfl_xor(se, off);
        const float wvv = ev * (1.f / (se + 1e-16f));

        const int cs0 = c0, cs1 = cnt - c0;
        const int itmax = (max(cs0, cs1) + 1) >> 1;   // NSLOT=2

        f32x2 acc0[4], acc1[4];
        #pragma unroll
        for (int i = 0; i < 4; ++i) { acc0[i] = (f32x2){0.f, 0.f}; acc1[i] = (f32x2){0.f, 0.f}; }

        int k = 0;
        // 4-step unroll: 8 loads issued before any fma (covers itmax<=4 = deg<=16/seg)
        for (; k + 4 <= itmax; k += 4) {
            int ee[4];
            int   ps[8]; float ws[8];
            #pragma unroll
            for (int u = 0; u < 4; ++u) {
                ee[u] = slot + (k + u) * 2;
                ps[u]     = __shfl(pv, ee[u]);
                ws[u]     = __shfl(wvv, ee[u]);
                int s1i   = min(c0 + ee[u], 63);
                ps[4 + u] = __shfl(pv, s1i);
                ws[4 + u] = __shfl(wvv, s1i);
            }
            #pragma unroll
            for (int u = 0; u < 4; ++u) {
                if (ee[u] >= cs0) { ws[u] = 0.f;     ps[u] = 0; }
                if (ee[u] >= cs1) { ws[4 + u] = 0.f; ps[4 + u] = 0; }
            }
            u32x4 r[8];
            #pragma unroll
            for (int u = 0; u < 8; ++u)
                r[u] = *(const u32x4*)(A1 + (long long)ps[u] * 256 + hl * 8);
            #pragma unroll
            for (int u = 0; u < 4; ++u) {
                fma8v(acc0, ws[u],     r[u]);
                fma8v(acc1, ws[4 + u], r[4 + u]);
            }
        }
        for (; k + 2 <= itmax; k += 2) {
            const int e00 = slot + k * 2, e01 = e00 + 2;
            int   p00 = __shfl(pv, e00);               float w00 = __shfl(wvv, e00);
            int   p01 = __shfl(pv, e01);               float w01 = __shfl(wvv, e01);
            const int s10 = min(c0 + e00, 63), s11 = min(c0 + e01, 63);
            int   p10 = __shfl(pv, s10);               float w10 = __shfl(wvv, s10);
            int   p11 = __shfl(pv, s11);               float w11 = __shfl(wvv, s11);
            if (e00 >= cs0) { w00 = 0.f; p00 = 0; }
            if (e01 >= cs0) { w01 = 0.f; p01 = 0; }
            if (e00 >= cs1) { w10 = 0.f; p10 = 0; }
            if (e01 >= cs1) { w11 = 0.f; p11 = 0; }
            const u32x4 r00 = *(const u32x4*)(A1 + (long long)p00 * 256 + hl * 8);
            const u32x4 r10 = *(const u32x4*)(A1 + (long long)p10 * 256 + hl * 8);
            const u32x4 r01 = *(const u32x4*)(A1 + (long long)p01 * 256 + hl * 8);
            const u32x4 r11 = *(const u32x4*)(A1 + (long long)p11 * 256 + hl * 8);
            fma8v(acc0, w00, r00);
            fma8v(acc1, w10, r10);
            fma8v(acc0, w01, r01);
            fma8v(acc1, w11, r11);
        }
        if (k < itmax) {
            const int e00 = slot + k * 2;
            int   p00 = __shfl(pv, e00);               float w00 = __shfl(wvv, e00);
            const int s10 = min(c0 + e00, 63);
            int   p10 = __shfl(pv, s10);               float w10 = __shfl(wvv, s10);
            if (e00 >= cs0) { w00 = 0.f; p00 = 0; }
            if (e00 >= cs1) { w10 = 0.f; p10 = 0; }
            const u32x4 r00 = *(const u32x4*)(A1 + (long long)p00 * 256 + hl * 8);
            const u32x4 r10 = *(const u32x4*)(A1 + (long long)p10 * 256 + hl * 8);
            fma8v(acc0, w00, r00);
            fma8v(acc1, w10, r10);
        }

        // slot reduce + write both segments
        #pragma unroll
        for (int t2 = 0; t2 < 4; ++t2) {
            acc0[t2].x += __shfl_xor(acc0[t2].x, 32);
            acc0[t2].y += __shfl_xor(acc0[t2].y, 32);
            acc1[t2].x += __shfl_xor(acc1[t2].x, 32);
            acc1[t2].y += __shfl_xor(acc1[t2].y, 32);
        }
        if (slot == 0) {
            u32x4 pack0, pack1;
            #pragma unroll
            for (int t2 = 0; t2 < 4; ++t2) {
                pack0[t2] = (unsigned)f2bf(acc0[t2].x) | ((unsigned)f2bf(acc0[t2].y) << 16);
                pack1[t2] = (unsigned)f2bf(acc1[t2].x) | ((unsigned)f2bf(acc1[t2].y) << 16);
            }
            *(u32x4*)(z + (long long)d * 512 + hl * 8)       = pack0;
            *(u32x4*)(z + (long long)d * 512 + 256 + hl * 8) = pack1;
        }
        return;
    }

    // ---- slow path (union degree > 64): 3-pass chunked ----
    float mx = -INFINITY;
    for (int j = start + lane; j < end; j += 64) {
        int s = epk[j];
        bool r1 = j >= mid;
        float a = (r1 ? q1 : q0) + kn[(r1 ? n : 0) + s];
        a = a > 0.f ? a : NEG_SLOPE * a;
        mx = fmaxf(mx, a);
    }
    #pragma unroll
    for (int off = 32; off; off >>= 1) mx = fmaxf(mx, __shfl_xor(mx, off));

    float se = 0.f;
    for (int j = start + lane; j < end; j += 64) {
        int s = epk[j];
        bool r1 = j >= mid;
        float a = (r1 ? q1 : q0) + kn[(r1 ? n : 0) + s];
        a = a > 0.f ? a : NEG_SLOPE * a;
        se += __expf(a - mx);
    }
    #pragma unroll
    for (int off = 32; off; off >>= 1) se += __shfl_xor(se, off);
    const float inv = 1.f / (se + 1e-16f);

    #pragma unroll
    for (int seg = 0; seg < 2; ++seg) {
        const int s0 = seg ? mid : start;
        const int s1 = seg ? end : mid;
        const float qr = seg ? q1 : q0;
        const int kbase = seg ? n : 0;

        float accA[8], accB[8];
        #pragma unroll
        for (int i = 0; i < 8; ++i) { accA[i] = 0.f; accB[i] = 0.f; }

        for (int base = s0; base < s1; base += 64) {
            const int cnt2 = min(64, s1 - base);
            int pv = 0; float wvv = 0.f;
            if (lane < cnt2) {
                pv = epk[base + lane];
                float a = qr + kn[kbase + pv];
                a = a > 0.f ? a : NEG_SLOPE * a;
                wvv = __expf(a - mx) * inv;
            }
            const int iters = (cnt2 + 1) >> 1;
            int k = 0;
            for (; k + 2 <= iters; k += 2) {
                const int e0 = slot + k * 2;
                const int e1 = e0 + 2;
                int   pA = __shfl(pv, e0);
                float wA = __shfl(wvv, e0);
                int   pB = __shfl(pv, e1);
                float wB = __shfl(wvv, e1);
                const u32x4 rA = *(const u32x4*)(A1 + (long long)pA * 256 + hl * 8);
                const u32x4 rB = *(const u32x4*)(A1 + (long long)pB * 256 + hl * 8);
                fma8s(accA, wA, rA);
                fma8s(accB, wB, rB);
            }
            if (k < iters) {
                const int e0 = slot + k * 2;
                int   pA = __shfl(pv, e0);
                float wA = __shfl(wvv, e0);
                const u32x4 rA = *(const u32x4*)(A1 + (long long)pA * 256 + hl * 8);
                fma8s(accA, wA, rA);
            }
        }

        float acc[8];
        #pragma unroll
        for (int i = 0; i < 8; ++i) acc[i] = accA[i] + accB[i];
        #pragma unroll
        for (int t2 = 0; t2 < 8; ++t2) acc[t2] += __shfl_xor(acc[t2], 32);

        if (slot == 0) {
            u32x4 pack;
            #pragma unroll
            for (int t2 = 0; t2 < 4; ++t2)
                pack[t2] = (unsigned)f2bf(acc[2 * t2]) | ((unsigned)f2bf(acc[2 * t2 + 1]) << 16);
            *(u32x4*)(z + (long long)d * 512 + seg * 256 + hl * 8) = pack;
        }
    }
}

// ---------------------------------------------------------------------------
// Layer-2 aggregation (C=64): gather xw2[et] rows; et positional (j>=mid).
// Fast path for union degree <= 64. Uniform shfls only. (round-10 validated)
// ---------------------------------------------------------------------------
__global__ __launch_bounds__(256) void aggregate2(
    const unsigned short* __restrict__ xw,   // [2][MPAD][64] bf16
    const float* __restrict__ qn,            // [2][n]
    const float* __restrict__ kn,            // [2][n]
    const int* __restrict__ row_ptr2,
    const int* __restrict__ epk,
    unsigned short* __restrict__ outb,       // [n][64] bf16 (ELU)
    float* __restrict__ outf,                // [n][64] f32
    int n)
{
    constexpr int LPE   = 8;     // 64 ch / 8 per lane
    constexpr int NSLOT = 8;

    const int wv   = ((blockIdx.x << 8) + threadIdx.x) >> 6;
    const int lane = threadIdx.x & 63;
    if (wv >= n) return;
    const int d = wv;
    const int start = row_ptr2[2 * d];
    const int mid   = row_ptr2[2 * d + 1];
    const int end   = row_ptr2[2 * d + 2];
    const int cnt = end - start;
    const int c0  = mid - start;
    const float q0 = qn[d];
    const float q1 = qn[n + d];
    const int slot = lane / LPE;
    const int hl   = lane % LPE;

    auto fma8 = [](float acc[8], float w, const u32x4& r) {
        #pragma unroll
        for (int t2 = 0; t2 < 4; ++t2) {
            unsigned dw = r[t2];
            acc[2 * t2]     = fmaf(w, __uint_as_float(dw << 16),         acc[2 * t2]);
            acc[2 * t2 + 1] = fmaf(w, __uint_as_float(dw & 0xFFFF0000u), acc[2 * t2 + 1]);
        }
    };

    float accA[8], accB[8];
    #pragma unroll
    for (int i = 0; i < 8; ++i) { accA[i] = 0.f; accB[i] = 0.f; }

    if (cnt <= 64) {
        // ---- fast path ----
        int pv = 0; float a = -INFINITY;
        if (lane < cnt) {
            pv = epk[start + lane];
            bool r1 = lane >= c0;
            a = (r1 ? q1 : q0) + kn[(r1 ? n : 0) + pv];
            a = a > 0.f ? a : NEG_SLOPE * a;
        }
        float mx = a;
        #pragma unroll
        for (int off = 32; off; off >>= 1) mx = fmaxf(mx, __shfl_xor(mx, off));
        float ev = (lane < cnt) ? __expf(a - mx) : 0.f;
        float se = ev;
        #pragma unroll
        for (int off = 32; off; off >>= 1) se += __shfl_xor(se, off);
        const float wvn = ev * (1.f / (se + 1e-16f));

        const int iters = (cnt + NSLOT - 1) / NSLOT;
        int k = 0;
        for (; k + 2 <= iters; k += 2) {
            const int e0 = slot + k * NSLOT;
            const int e1 = e0 + NSLOT;
            int   pA = __shfl(pv, e0);
            float wA = __shfl(wvn, e0);
            int   pB = __shfl(pv, e1);
            float wB = __shfl(wvn, e1);
            const long long oA = ((e0 >= c0) ? (long long)MPAD * 64 : 0) + (long long)pA * 64 + hl * 8;
            const long long oB = ((e1 >= c0) ? (long long)MPAD * 64 : 0) + (long long)pB * 64 + hl * 8;
            const u32x4 rA = *(const u32x4*)(xw + oA);
            const u32x4 rB = *(const u32x4*)(xw + oB);
            fma8(accA, wA, rA);
            fma8(accB, wB, rB);
        }
        if (k < iters) {
            const int e0 = slot + k * NSLOT;
            int   pA = __shfl(pv, e0);
            float wA = __shfl(wvn, e0);
            const long long oA = ((e0 >= c0) ? (long long)MPAD * 64 : 0) + (long long)pA * 64 + hl * 8;
            const u32x4 rA = *(const u32x4*)(xw + oA);
            fma8(accA, wA, rA);
        }
    } else {
        // ---- slow path: 3-pass chunked ----
        float mx = -INFINITY;
        for (int j = start + lane; j < end; j += 64) {
            int s = epk[j];
            bool r1 = j >= mid;
            float a = (r1 ? q1 : q0) + kn[(r1 ? n : 0) + s];
            a = a > 0.f ? a : NEG_SLOPE * a;
            mx = fmaxf(mx, a);
        }
        #pragma unroll
        for (int off = 32; off; off >>= 1) mx = fmaxf(mx, __shfl_xor(mx, off));

        float se = 0.f;
        for (int j = start + lane; j < end; j += 64) {
            int s = epk[j];
            bool r1 = j >= mid;
            float a = (r1 ? q1 : q0) + kn[(r1 ? n : 0) + s];
            a = a > 0.f ? a : NEG_SLOPE * a;
            se += __expf(a - mx);
        }
        #pragma unroll
        for (int off = 32; off; off >>= 1) se += __shfl_xor(se, off);
        const float inv = 1.f / (se + 1e-16f);

        for (int base = start; base < end; base += 64) {
            const int cnt2 = min(64, end - base);
            int pv = 0; float wvn = 0.f;
            if (lane < cnt2) {
                int j = base + lane;
                pv = epk[j];
                bool r1 = j >= mid;
                float a = (r1 ? q1 : q0) + kn[(r1 ? n : 0) + pv];
                a = a > 0.f ? a : NEG_SLOPE * a;
                wvn = __expf(a - mx) * inv;
            }
            const int iters = (cnt2 + NSLOT - 1) / NSLOT;
            int k = 0;
            for (; k + 2 <= iters; k += 2) {
                const int e0 = slot + k * NSLOT;
                const int e1 = e0 + NSLOT;
                int   pA = __shfl(pv, e0);
                float wA = __shfl(wvn, e0);
                int   pB = __shfl(pv, e1);
                float wB = __shfl(wvn, e1);
                const long long oA = ((base + e0 >= mid) ? (long long)MPAD * 64 : 0) + (long long)pA * 64 + hl * 8;
                const long long oB = ((base + e1 >= mid) ? (long long)MPAD * 64 : 0) + (long long)pB * 64 + hl * 8;
                const u32x4 rA = *(const u32x4*)(xw + oA);
                const u32x4 rB = *(const u32x4*)(xw + oB);
                fma8(accA, wA, rA);
                fma8(accB, wB, rB);
            }
            if (k < iters) {
                const int e0 = slot + k * NSLOT;
                int   pA = __shfl(pv, e0);
                float wA = __shfl(wvn, e0);
                const long long oA = ((base + e0 >= mid) ? (long long)MPAD * 64 : 0) + (long long)pA * 64 + hl * 8;
                const u32x4 rA = *(const u32x4*)(xw + oA);
                fma8(accA, wA, rA);
            }
        }
    }

    float acc[8];
    #pragma unroll
    for (int i = 0; i < 8; ++i) acc[i] = accA[i] + accB[i];
    #pragma unroll
    for (int off = LPE; off < 64; off <<= 1)
        #pragma unroll
        for (int t2 = 0; t2 < 8; ++t2) acc[t2] += __shfl_xor(acc[t2], off);

    if (slot == 0) {
        float fo[8];
        #pragma unroll
        for (int t2 = 0; t2 < 8; ++t2) fo[t2] = elu(acc[t2]);
        u32x4 pack;
        #pragma unroll
        for (int t2 = 0; t2 < 4; ++t2)
            pack[t2] = (unsigned)f2bf(fo[2 * t2]) | ((unsigned)f2bf(fo[2 * t2 + 1]) << 16);
        *(u32x4*)(outb + (long long)d * 64 + hl * 8) = pack;
        *(float4*)(outf + (long long)d * 64 + hl * 8)     = make_float4(fo[0], fo[1], fo[2], fo[3]);
        *(float4*)(outf + (long long)d * 64 + hl * 8 + 4) = make_float4(fo[4], fo[5], fo[6], fo[7]);
    }
}

// ---------------------------------------------------------------------------
extern "C" void kernel_launch(void* const* d_in, const int* in_sizes, int n_in,
                              void* d_out, int out_size, void* d_ws, size_t ws_size,
                              hipStream_t stream)
{
    const float* features = (const float*)d_in[0];
    const int*   ei       = (const int*)d_in[1];
    const int*   etype    = (const int*)d_in[2];
    const float* w1       = (const float*)d_in[3];
    const float* q1       = (const float*)d_in[4];
    const float* k1       = (const float*)d_in[5];
    const float* w2       = (const float*)d_in[6];
    const float* q2       = (const float*)d_in[7];
    const float* k2       = (const float*)d_in[8];
    const float* dW1      = (const float*)d_in[9];
    const float* db1      = (const float*)d_in[10];
    const float* dW2      = (const float*)d_in[11];
    const float* db2      = (const float*)d_in[12];

    const int n = in_sizes[0] / IN_DIM;   // 50000
    const int E = in_sizes[2];            // 800000
    const int n2 = 2 * n;
    const int* src = ei;
    const int* dst = ei + E;

    float* out_h2 = (float*)d_out;                      // [n][64]
    float* out_h3 = out_h2 + (long long)n * OUT_D;      // [n][200]

    char* wp = (char*)d_ws;
    auto carve = [&](size_t bytes) {
        char* p = wp; wp += (bytes + 255) & ~(size_t)255; return p;
    };
    unsigned short* A1   = (unsigned short*)carve((size_t)MPAD * 256 * 2);
    unsigned short* zbuf = (unsigned short*)carve((size_t)MPAD * 512 * 2);
    unsigned short* h1   = (unsigned short*)carve((size_t)MPAD * 256 * 2);
    unsigned short* xw2  = (unsigned short*)carve((size_t)2 * MPAD * 64 * 2);
    unsigned short* h2b  = (unsigned short*)carve((size_t)MPAD * 64 * 2);
    unsigned short* tdec = (unsigned short*)carve((size_t)MPAD * 256 * 2);
    unsigned short* wst  = (unsigned short*)carve((size_t)256 * 512 * 2);
    unsigned short* w2t  = (unsigned short*)carve((size_t)2 * 64 * 256 * 2);
    unsigned short* dW1t = (unsigned short*)carve((size_t)256 * 64 * 2);
    unsigned short* dW2t = (unsigned short*)carve((size_t)256 * 256 * 2);
    float* wqv    = (float*)carve((size_t)2 * 256 * 4);
    float* wkv    = (float*)carve((size_t)2 * 256 * 4);
    float* qnb1   = (float*)carve((size_t)n2 * 4);
    float* knb1   = (float*)carve((size_t)n2 * 4);
    float* qnb2   = (float*)carve((size_t)n2 * 4);
    float* knb2   = (float*)carve((size_t)n2 * 4);
    int* row_ptr2 = (int*)carve((size_t)(n2 + 1) * 4);
    int* cursor2  = (int*)carve((size_t)n2 * 4);
    int* deg2     = (int*)carve((size_t)n2 * 4);
    int* bsum     = (int*)carve((size_t)512 * 4);
    int* epk      = (int*)carve((size_t)E * 4);

    const int EB  = (E + 255) / 256;
    const int NB2 = (n2 + 255) / 256;          // 391 (scan_bsum handles <=512)
    const int MB  = (n + 127) / 128;           // 391
    const int WAVE_N = (n + 3) / 4;

    // ---- merged prep: converts + wqk + zeroing (deg2, qnb2/knb2) ----
    prep_all<<<PB_QK2, 256, 0, stream>>>(features, w1, w2, dW1, dW2, q1, k1,
                                         A1, wst, w2t, dW1t, dW2t,
                                         wqv, wkv, deg2, qnb2, knb2, n2);

    // ---- CSR build (relation-segmented) ----
    count_kernel<<<EB, 256, 0, stream>>>(dst, etype, deg2, E);
    scan_blocksum<<<NB2, 256, 0, stream>>>(deg2, bsum, n2);
    scan_bsum<<<1, 512, 0, stream>>>(bsum, NB2);
    scan_final<<<NB2, 256, 0, stream>>>(deg2, bsum, row_ptr2, cursor2, n2);
    scatter_kernel<<<EB, 256, 0, stream>>>(dst, src, etype, cursor2, epk, E);

    // ---- layer 1: qk from features, segmented z-aggregation, K=512 GEMM+ELU ----
    qk_feat<<<WAVE_N, 256, 0, stream>>>(A1, wqv, wkv, qnb1, knb1, n);
    aggregate_z<<<WAVE_N, 256, 0, stream>>>(A1, qnb1, knb1, row_ptr2, epk, zbuf, n);
    {
        dim3 g(MB, 4, 1);
        gemm_mfma<true, true, false><<<g, 256, 0, stream>>>(zbuf, wst, nullptr, h1,
                                                            nullptr, nullptr, nullptr, nullptr,
                                                            n, HID, 512, 256, 0);
    }

    // ---- layer 2 (q/k fused into GEMM epilogue; qnb2/knb2 zeroed in prep) ----
    {
        dim3 g(MB, 1, RREL);
        gemm_mfma<true, false, true><<<g, 256, 0, stream>>>(h1, w2t, nullptr, xw2,
                                                            q2, k2, qnb2, knb2,
                                                            n, OUT_D, 256, 64, (long long)MPAD * OUT_D);
    }
    aggregate2<<<WAVE_N, 256, 0, stream>>>(xw2, qnb2, knb2, row_ptr2, epk,
                                           h2b, out_h2, n);

    // ---- decoder ----
    {
        dim3 g(MB, 4, 1);
        gemm_mfma<true, false, false><<<g, 256, 0, stream>>>(h2b, dW1t, db1, tdec,
                                                             nullptr, nullptr, nullptr, nullptr,
                                                             n, HID, 64, 256, 0);
    }
    {
        dim3 g(MB, 4, 1);
        gemm_mfma<false, false, false><<<g, 256, 0, stream>>>(tdec, dW2t, db2, out_h3,
                                                              nullptr, nullptr, nullptr, nullptr,
                                                              n, IN_DIM, 256, 256, 0);
    }
}

// Round 13
// 327.119 us; speedup vs baseline: 1.0382x; 1.0382x over previous
//
#include <hip/hip_runtime.h>

#define IN_DIM 200
#define HID    256
#define OUT_D  64
#define RREL   2
#define NEG_SLOPE 0.2f
#define NNODE  50000
#define MPAD   50048          // ceil(50000/128)*128 — staging-safe row pad

typedef __attribute__((ext_vector_type(8))) short bf16x8;
typedef __attribute__((ext_vector_type(4))) float f32x4;
typedef __attribute__((ext_vector_type(2))) float f32x2;
typedef __attribute__((ext_vector_type(4))) unsigned int u32x4;

__device__ __forceinline__ float bf2f(unsigned short u) {
    union { unsigned int i; float f; } v; v.i = ((unsigned int)u) << 16; return v.f;
}
__device__ __forceinline__ unsigned short f2bf(float f) {
    union { float f; unsigned int i; } v; v.f = f;
    unsigned int u = v.i;
    return (unsigned short)((u + 0x7FFFu + ((u >> 16) & 1u)) >> 16);   // RNE
}
__device__ __forceinline__ float elu(float v) { return v > 0.f ? v : (__expf(v) - 1.0f); }

// ---------------------------------------------------------------------------
// Merged prep kernel: all weight/feature converts + wqk + buffer zeroing.
// ---------------------------------------------------------------------------
__device__ __forceinline__ void wt_cvt_body(
    const float* __restrict__ in, unsigned short* __restrict__ out,
    int Kreal, int Nreal, int Kpad, int Npad, int nb, long long idx)
{
    long long total = (long long)nb * Npad * Kpad;
    if (idx >= total) return;
    int kk = (int)(idx % Kpad);
    long long t = idx / Kpad;
    int nrow = (int)(t % Npad);
    int z = (int)(t / Npad);
    float f = (kk < Kreal && nrow < Nreal) ? in[((long long)z * Kreal + kk) * Nreal + nrow] : 0.f;
    out[idx] = f2bf(f);
}

#define PB_FEAT   12512                    // feat_cvt: MPAD*64/256
#define PB_WST    (PB_FEAT + 512)          // wt_cvt_stack
#define PB_W2T    (PB_WST + 128)           // w2 -> w2t
#define PB_DW1    (PB_W2T + 64)            // dW1 -> dW1t
#define PB_DW2    (PB_DW1 + 256)           // dW2 -> dW2t
#define PB_WQK    (PB_DW2 + 128)           // wqk
#define PB_DEG    (PB_WQK + 391)           // deg2 zero
#define PB_QK2    (PB_DEG + 391)           // qnb2/knb2 zero

__global__ __launch_bounds__(256) void prep_all(
    const float* __restrict__ features, const float* __restrict__ w1,
    const float* __restrict__ w2, const float* __restrict__ dW1,
    const float* __restrict__ dW2, const float* __restrict__ q1,
    const float* __restrict__ k1,
    unsigned short* __restrict__ A1, unsigned short* __restrict__ wst,
    unsigned short* __restrict__ w2t, unsigned short* __restrict__ dW1t,
    unsigned short* __restrict__ dW2t, float* __restrict__ wqv,
    float* __restrict__ wkv, int* __restrict__ deg2,
    float* __restrict__ qnb2, float* __restrict__ knb2, int n2)
{
    const int b = blockIdx.x;
    const int tid = threadIdx.x;

    if (b < PB_FEAT) {
        long long idx = (long long)b * 256 + tid;
        int row = (int)(idx >> 6);
        int c4  = ((int)idx & 63) << 2;
        if (row >= MPAD) return;
        unsigned short v[4];
        #pragma unroll
        for (int i = 0; i < 4; ++i) {
            int c = c4 + i;
            float f = (row < NNODE && c < IN_DIM) ? features[(long long)row * IN_DIM + c] : 0.f;
            v[i] = f2bf(f);
        }
        *(ushort4*)(A1 + (long long)row * 256 + c4) = make_ushort4(v[0], v[1], v[2], v[3]);
    } else if (b < PB_WST) {
        int idx = (b - PB_FEAT) * 256 + tid;
        if (idx >= 2 * 256 * 256) return;
        int kk = idx & 255;
        int c  = (idx >> 8) & 255;
        int z  = idx >> 16;
        float f = (kk < IN_DIM) ? w1[((long long)z * IN_DIM + kk) * 256 + c] : 0.f;
        wst[(long long)c * 512 + z * 256 + kk] = f2bf(f);
    } else if (b < PB_W2T) {
        wt_cvt_body(w2, w2t, HID, OUT_D, 256, 64, RREL, (long long)(b - PB_WST) * 256 + tid);
    } else if (b < PB_DW1) {
        wt_cvt_body(dW1, dW1t, OUT_D, HID, 64, 256, 1, (long long)(b - PB_W2T) * 256 + tid);
    } else if (b < PB_DW2) {
        wt_cvt_body(dW2, dW2t, HID, IN_DIM, 256, 256, 1, (long long)(b - PB_DW1) * 256 + tid);
    } else if (b < PB_WQK) {
        int wv = (((b - PB_DW2) << 8) + tid) >> 6;
        int lane = tid & 63;
        if (wv >= 512) return;
        int r = wv >> 8, kk = wv & 255;
        float sq = 0.f, sk = 0.f;
        if (kk < IN_DIM) {                   // wave-uniform (kk from wave id)
            const float* row = w1 + ((long long)(r * IN_DIM + kk)) * 256;
            float4 wv4 = *(const float4*)(row + lane * 4);
            float4 qv4 = *(const float4*)(q1 + lane * 4);
            float4 kv4 = *(const float4*)(k1 + lane * 4);
            sq = wv4.x * qv4.x + wv4.y * qv4.y + wv4.z * qv4.z + wv4.w * qv4.w;
            sk = wv4.x * kv4.x + wv4.y * kv4.y + wv4.z * kv4.z + wv4.w * kv4.w;
            #pragma unroll
            for (int off = 32; off; off >>= 1) {
                sq += __shfl_xor(sq, off);
                sk += __shfl_xor(sk, off);
            }
        }
        if (lane == 0) { wqv[r * 256 + kk] = sq; wkv[r * 256 + kk] = sk; }
    } else if (b < PB_DEG) {
        int i = (b - PB_WQK) * 256 + tid;
        if (i < n2) deg2[i] = 0;
    } else if (b < PB_QK2) {
        int i = (b - PB_DEG) * 256 + tid;
        if (i < n2) { qnb2[i] = 0.f; knb2[i] = 0.f; }
    }
}

// qn/kn for layer 1 from padded features: one wave per node, both relations.
__global__ __launch_bounds__(256) void qk_feat(
    const unsigned short* __restrict__ A1, const float* __restrict__ wqv,
    const float* __restrict__ wkv, float* __restrict__ qn, float* __restrict__ kn, int n)
{
    int wv = ((blockIdx.x << 8) + threadIdx.x) >> 6;
    int lane = threadIdx.x & 63;
    if (wv >= n) return;
    ushort4 v = *(const ushort4*)(A1 + (long long)wv * 256 + lane * 4);
    float x0 = bf2f(v.x), x1 = bf2f(v.y), x2 = bf2f(v.z), x3 = bf2f(v.w);
    float4 q0v = *(const float4*)(wqv + lane * 4);
    float4 k0v = *(const float4*)(wkv + lane * 4);
    float4 q1v = *(const float4*)(wqv + 256 + lane * 4);
    float4 k1v = *(const float4*)(wkv + 256 + lane * 4);
    float sq0 = x0 * q0v.x + x1 * q0v.y + x2 * q0v.z + x3 * q0v.w;
    float sk0 = x0 * k0v.x + x1 * k0v.y + x2 * k0v.z + x3 * k0v.w;
    float sq1 = x0 * q1v.x + x1 * q1v.y + x2 * q1v.z + x3 * q1v.w;
    float sk1 = x0 * k1v.x + x1 * k1v.y + x2 * k1v.z + x3 * k1v.w;
    #pragma unroll
    for (int off = 32; off; off >>= 1) {
        sq0 += __shfl_xor(sq0, off);
        sk0 += __shfl_xor(sk0, off);
        sq1 += __shfl_xor(sq1, off);
        sk1 += __shfl_xor(sk1, off);
    }
    if (lane == 0) {
        qn[wv] = sq0; qn[n + wv] = sq1;
        kn[wv] = sk0; kn[n + wv] = sk1;
    }
}

// ---------------------------------------------------------------------------
// bf16 MFMA GEMM (optional fused ELU / fused q,k row-dots via atomicAdd).
// ---------------------------------------------------------------------------
template<bool OUT_BF16, bool DO_ELU, bool FUSE_QK>
__global__ __launch_bounds__(256) void gemm_mfma(
    const unsigned short* __restrict__ A,
    const unsigned short* __restrict__ Bt,
    const float* __restrict__ bias,
    void* __restrict__ Cout,
    const float* __restrict__ qvec, const float* __restrict__ kvec,
    float* __restrict__ qn_out, float* __restrict__ kn_out,
    int M, int Nn, int Kp, int Npad,
    long long strideC)
{
    __shared__ __align__(16) char lds[49152];   // 2 x (A 16KB + B 8KB)
    const int tid  = threadIdx.x;
    const int lane = tid & 63;
    const int w    = tid >> 6;
    const int m0   = blockIdx.x * 128;
    const int n0   = blockIdx.y * 64;
    const int z    = blockIdx.z;

    const char* Ab = (const char*)A;
    const char* Bb = (const char*)(Bt + (long long)z * Npad * Kp);
    const int rs = Kp * 2;

    f32x4 acc[2][4];
    #pragma unroll
    for (int i = 0; i < 2; ++i)
        #pragma unroll
        for (int j = 0; j < 4; ++j) acc[i][j] = (f32x4){0.f, 0.f, 0.f, 0.f};

    const int KT = Kp >> 6;

    auto stage = [&](int buf, int kt) {
        char* lA = lds + buf * 24576;
        char* lB = lA + 16384;
        #pragma unroll
        for (int i = 0; i < 4; ++i) {
            int g = i * 256 + tid;
            int row = g >> 3, c = g & 7;
            const char* src = Ab + (long long)(m0 + row) * rs + kt * 128 + ((c ^ (row & 7)) << 4);
            __builtin_amdgcn_global_load_lds((const __attribute__((address_space(1))) void*)src,
                                             (__attribute__((address_space(3))) void*)(lA + g * 16),
                                             16, 0, 0);
        }
        #pragma unroll
        for (int i = 0; i < 2; ++i) {
            int g = i * 256 + tid;
            int row = g >> 3, c = g & 7;
            const char* src = Bb + (long long)(n0 + row) * rs + kt * 128 + ((c ^ (row & 7)) << 4);
            __builtin_amdgcn_global_load_lds((const __attribute__((address_space(1))) void*)src,
                                             (__attribute__((address_space(3))) void*)(lB + g * 16),
                                             16, 0, 0);
        }
    };

    stage(0, 0);
    int cur = 0;
    for (int kt = 0; kt < KT; ++kt) {
        __syncthreads();
        if (kt + 1 < KT) stage(cur ^ 1, kt + 1);
        const char* lA = lds + cur * 24576;
        const char* lB = lA + 16384;
        #pragma unroll
        for (int ks = 0; ks < 2; ++ks) {
            const int kg = ks * 4 + (lane >> 4);
            bf16x8 a[2], b[4];
            #pragma unroll
            for (int mi = 0; mi < 2; ++mi) {
                int row = w * 32 + mi * 16 + (lane & 15);
                a[mi] = *(const bf16x8*)(lA + row * 128 + ((kg ^ (row & 7)) << 4));
            }
            #pragma unroll
            for (int nj = 0; nj < 4; ++nj) {
                int row = nj * 16 + (lane & 15);
                b[nj] = *(const bf16x8*)(lB + row * 128 + ((kg ^ (row & 7)) << 4));
            }
            #pragma unroll
            for (int mi = 0; mi < 2; ++mi)
                #pragma unroll
                for (int nj = 0; nj < 4; ++nj)
                    acc[mi][nj] = __builtin_amdgcn_mfma_f32_16x16x32_bf16(a[mi], b[nj], acc[mi][nj], 0, 0, 0);
        }
        cur ^= 1;
    }

    // epilogue: C/D layout col=lane&15, row=(lane>>4)*4+r
    const int colb = n0 + (lane & 15);
    #pragma unroll
    for (int mi = 0; mi < 2; ++mi) {
        #pragma unroll
        for (int nj = 0; nj < 4; ++nj) {
            int col = colb + nj * 16;
            if (col >= Nn) continue;
            float badd = bias ? bias[col] : 0.f;
            #pragma unroll
            for (int r = 0; r < 4; ++r) {
                int rowm = m0 + w * 32 + mi * 16 + ((lane >> 4) << 2) + r;
                if (rowm >= M) continue;
                float v = acc[mi][nj][r] + badd;
                if (DO_ELU) v = v > 0.f ? v : (__expf(v) - 1.0f);
                if (OUT_BF16)
                    ((unsigned short*)Cout)[strideC * z + (long long)rowm * Nn + col] = f2bf(v);
                else
                    ((float*)Cout)[strideC * z + (long long)rowm * Nn + col] = v;
            }
        }
    }

    if (FUSE_QK) {
        float qv[4], kv[4];
        #pragma unroll
        for (int nj = 0; nj < 4; ++nj) {
            int col = colb + nj * 16;
            bool ok = col < Nn;
            qv[nj] = ok ? qvec[col] : 0.f;
            kv[nj] = ok ? kvec[col] : 0.f;
        }
        #pragma unroll
        for (int mi = 0; mi < 2; ++mi) {
            #pragma unroll
            for (int r = 0; r < 4; ++r) {
                float sq = 0.f, sk = 0.f;
                #pragma unroll
                for (int nj = 0; nj < 4; ++nj) {
                    sq = fmaf(acc[mi][nj][r], qv[nj], sq);
                    sk = fmaf(acc[mi][nj][r], kv[nj], sk);
                }
                #pragma unroll
                for (int off = 1; off < 16; off <<= 1) {   // full-wave, uniform
                    sq += __shfl_xor(sq, off);
                    sk += __shfl_xor(sk, off);
                }
                if ((lane & 15) == 0) {
                    int rowm = m0 + w * 32 + mi * 16 + ((lane >> 4) << 2) + r;
                    if (rowm < M) {
                        atomicAdd(qn_out + (long long)z * M + rowm, sq);
                        atomicAdd(kn_out + (long long)z * M + rowm, sk);
                    }
                }
            }
        }
    }
}

// ---------------------------------------------------------------------------
// CSR build — relation-segmented: counters indexed 2*dst + etype
// ---------------------------------------------------------------------------
__global__ void count_kernel(const int* __restrict__ dst, const int* __restrict__ etype,
                             int* __restrict__ deg2, int E)
{
    int e = blockIdx.x * 256 + threadIdx.x;
    if (e < E) atomicAdd(&deg2[(dst[e] << 1) | etype[e]], 1);
}

__global__ __launch_bounds__(256) void scan_blocksum(
    const int* __restrict__ deg, int* __restrict__ bsum, int n)
{
    __shared__ int red[256];
    int i = blockIdx.x * 256 + threadIdx.x;
    int v = (i < n) ? deg[i] : 0;
    red[threadIdx.x] = v;
    __syncthreads();
    #pragma unroll
    for (int off = 128; off; off >>= 1) {
        if (threadIdx.x < off) red[threadIdx.x] += red[threadIdx.x + off];
        __syncthreads();
    }
    if (threadIdx.x == 0) bsum[blockIdx.x] = red[0];
}

// exclusive scan of <=512 block sums (single block, 512 threads)
__global__ __launch_bounds__(512) void scan_bsum(int* __restrict__ bsum, int nb)
{
    __shared__ int buf[512];
    const int t = threadIdx.x;
    int v = (t < nb) ? bsum[t] : 0;
    buf[t] = v;
    __syncthreads();
    #pragma unroll
    for (int off = 1; off < 512; off <<= 1) {
        int u = (t >= off) ? buf[t - off] : 0;
        __syncthreads();
        buf[t] += u;
        __syncthreads();
    }
    if (t < nb) bsum[t] = buf[t] - v;   // exclusive
}

__global__ __launch_bounds__(256) void scan_final(
    const int* __restrict__ deg, const int* __restrict__ bsum,
    int* __restrict__ row_ptr, int* __restrict__ cursor, int n)
{
    __shared__ int buf[256];
    const int t = threadIdx.x;
    const int i = blockIdx.x * 256 + t;
    int v = (i < n) ? deg[i] : 0;
    buf[t] = v;
    __syncthreads();
    #pragma unroll
    for (int off = 1; off < 256; off <<= 1) {
        int u = (t >= off) ? buf[t - off] : 0;
        __syncthreads();
        buf[t] += u;
        __syncthreads();
    }
    int excl = bsum[blockIdx.x] + buf[t] - v;
    if (i < n) { row_ptr[i] = excl; cursor[i] = excl; }
    if (i == n - 1) row_ptr[n] = excl + v;
}

__global__ void scatter_kernel(const int* __restrict__ dst, const int* __restrict__ src,
                               const int* __restrict__ etype, int* __restrict__ cursor2,
                               int* __restrict__ epk, int E)
{
    int e = blockIdx.x * 256 + threadIdx.x;
    if (e < E) {
        int p = atomicAdd(&cursor2[(dst[e] << 1) | etype[e]], 1);
        epk[p] = src[e];                 // plain src; relation implicit in segment
    }
}

// ---------------------------------------------------------------------------
// Layer-1 aggregation into z. Fast path (union degree <= 64, ~always):
// single-pass softmax, SEGMENT-INTERLEAVED gather (2 independent fma chains,
// 4 loads in flight, no inter-segment drain), pk-fma (f32x2), masked slots
// redirected to row 0 (hot line, no wasted random fetch).
// Slow path: 3-pass chunked (validated rounds 8-10). Uniform shfls only.
// (round-11 form — measured 62.5us; r12's occupancy trade regressed, reverted)
// ---------------------------------------------------------------------------
__global__ __launch_bounds__(256) void aggregate_z(
    const unsigned short* __restrict__ A1,   // [MPAD][256] bf16
    const float* __restrict__ qn,            // [2][n]
    const float* __restrict__ kn,            // [2][n]
    const int* __restrict__ row_ptr2,        // [2n+1]
    const int* __restrict__ epk,             // [E] src
    unsigned short* __restrict__ z,          // [MPAD][512] bf16
    int n)
{
    const int wv   = ((blockIdx.x << 8) + threadIdx.x) >> 6;
    const int lane = threadIdx.x & 63;
    if (wv >= n) return;
    const int d = wv;
    const int start = row_ptr2[2 * d];
    const int mid   = row_ptr2[2 * d + 1];
    const int end   = row_ptr2[2 * d + 2];
    const int cnt = end - start;
    const int c0  = mid - start;
    const float q0 = qn[d];
    const float q1 = qn[n + d];
    const int slot = lane >> 5;
    const int hl   = lane & 31;

    auto fma8v = [](f32x2 acc[4], float w, const u32x4& r) {
        #pragma unroll
        for (int t2 = 0; t2 < 4; ++t2) {
            f32x2 x;
            x.x = __uint_as_float(r[t2] << 16);
            x.y = __uint_as_float(r[t2] & 0xFFFF0000u);
            acc[t2] += w * x;               // -> v_pk_fma_f32
        }
    };
    auto fma8s = [](float acc[8], float w, const u32x4& r) {
        #pragma unroll
        for (int t2 = 0; t2 < 4; ++t2) {
            unsigned dw = r[t2];
            acc[2 * t2]     = fmaf(w, __uint_as_float(dw << 16),         acc[2 * t2]);
            acc[2 * t2 + 1] = fmaf(w, __uint_as_float(dw & 0xFFFF0000u), acc[2 * t2 + 1]);
        }
    };

    if (cnt <= 64) {
        // ---- fast path ----
        int pv = 0; float a = -INFINITY;
        if (lane < cnt) {
            pv = epk[start + lane];
            bool r1 = lane >= c0;
            a = (r1 ? q1 : q0) + kn[(r1 ? n : 0) + pv];
            a = a > 0.f ? a : NEG_SLOPE * a;
        }
        float mx = a;
        #pragma unroll
        for (int off = 32; off; off >>= 1) mx = fmaxf(mx, __shfl_xor(mx, off));
        float ev = (lane < cnt) ? __expf(a - mx) : 0.f;
        float se = ev;
        #pragma unroll
        for (int off = 32; off; off >>= 1) se += __shfl_xor(se, off);
        const float wvv = ev * (1.f / (se + 1e-16f));

        const int cs0 = c0, cs1 = cnt - c0;
        const int itmax = (max(cs0, cs1) + 1) >> 1;   // NSLOT=2

        f32x2 acc0[4], acc1[4];
        #pragma unroll
        for (int i = 0; i < 4; ++i) { acc0[i] = (f32x2){0.f, 0.f}; acc1[i] = (f32x2){0.f, 0.f}; }

        int k = 0;
        for (; k + 2 <= itmax; k += 2) {
            const int e00 = slot + k * 2, e01 = e00 + 2;
            int   p00 = __shfl(pv, e00);               float w00 = __shfl(wvv, e00);
            int   p01 = __shfl(pv, e01);               float w01 = __shfl(wvv, e01);
            const int s10 = min(c0 + e00, 63), s11 = min(c0 + e01, 63);
            int   p10 = __shfl(pv, s10);               float w10 = __shfl(wvv, s10);
            int   p11 = __shfl(pv, s11);               float w11 = __shfl(wvv, s11);
            if (e00 >= cs0) { w00 = 0.f; p00 = 0; }
            if (e01 >= cs0) { w01 = 0.f; p01 = 0; }
            if (e00 >= cs1) { w10 = 0.f; p10 = 0; }
            if (e01 >= cs1) { w11 = 0.f; p11 = 0; }
            const u32x4 r00 = *(const u32x4*)(A1 + (long long)p00 * 256 + hl * 8);
            const u32x4 r10 = *(const u32x4*)(A1 + (long long)p10 * 256 + hl * 8);
            const u32x4 r01 = *(const u32x4*)(A1 + (long long)p01 * 256 + hl * 8);
            const u32x4 r11 = *(const u32x4*)(A1 + (long long)p11 * 256 + hl * 8);
            fma8v(acc0, w00, r00);
            fma8v(acc1, w10, r10);
            fma8v(acc0, w01, r01);
            fma8v(acc1, w11, r11);
        }
        if (k < itmax) {
            const int e00 = slot + k * 2;
            int   p00 = __shfl(pv, e00);               float w00 = __shfl(wvv, e00);
            const int s10 = min(c0 + e00, 63);
            int   p10 = __shfl(pv, s10);               float w10 = __shfl(wvv, s10);
            if (e00 >= cs0) { w00 = 0.f; p00 = 0; }
            if (e00 >= cs1) { w10 = 0.f; p10 = 0; }
            const u32x4 r00 = *(const u32x4*)(A1 + (long long)p00 * 256 + hl * 8);
            const u32x4 r10 = *(const u32x4*)(A1 + (long long)p10 * 256 + hl * 8);
            fma8v(acc0, w00, r00);
            fma8v(acc1, w10, r10);
        }

        // slot reduce + write both segments
        #pragma unroll
        for (int t2 = 0; t2 < 4; ++t2) {
            acc0[t2].x += __shfl_xor(acc0[t2].x, 32);
            acc0[t2].y += __shfl_xor(acc0[t2].y, 32);
            acc1[t2].x += __shfl_xor(acc1[t2].x, 32);
            acc1[t2].y += __shfl_xor(acc1[t2].y, 32);
        }
        if (slot == 0) {
            u32x4 pack0, pack1;
            #pragma unroll
            for (int t2 = 0; t2 < 4; ++t2) {
                pack0[t2] = (unsigned)f2bf(acc0[t2].x) | ((unsigned)f2bf(acc0[t2].y) << 16);
                pack1[t2] = (unsigned)f2bf(acc1[t2].x) | ((unsigned)f2bf(acc1[t2].y) << 16);
            }
            *(u32x4*)(z + (long long)d * 512 + hl * 8)       = pack0;
            *(u32x4*)(z + (long long)d * 512 + 256 + hl * 8) = pack1;
        }
        return;
    }

    // ---- slow path (union degree > 64): 3-pass chunked ----
    float mx = -INFINITY;
    for (int j = start + lane; j < end; j += 64) {
        int s = epk[j];
        bool r1 = j >= mid;
        float a = (r1 ? q1 : q0) + kn[(r1 ? n : 0) + s];
        a = a > 0.f ? a : NEG_SLOPE * a;
        mx = fmaxf(mx, a);
    }
    #pragma unroll
    for (int off = 32; off; off >>= 1) mx = fmaxf(mx, __shfl_xor(mx, off));

    float se = 0.f;
    for (int j = start + lane; j < end; j += 64) {
        int s = epk[j];
        bool r1 = j >= mid;
        float a = (r1 ? q1 : q0) + kn[(r1 ? n : 0) + s];
        a = a > 0.f ? a : NEG_SLOPE * a;
        se += __expf(a - mx);
    }
    #pragma unroll
    for (int off = 32; off; off >>= 1) se += __shfl_xor(se, off);
    const float inv = 1.f / (se + 1e-16f);

    #pragma unroll
    for (int seg = 0; seg < 2; ++seg) {
        const int s0 = seg ? mid : start;
        const int s1 = seg ? end : mid;
        const float qr = seg ? q1 : q0;
        const int kbase = seg ? n : 0;

        float accA[8], accB[8];
        #pragma unroll
        for (int i = 0; i < 8; ++i) { accA[i] = 0.f; accB[i] = 0.f; }

        for (int base = s0; base < s1; base += 64) {
            const int cnt2 = min(64, s1 - base);
            int pv = 0; float wvv = 0.f;
            if (lane < cnt2) {
                pv = epk[base + lane];
                float a = qr + kn[kbase + pv];
                a = a > 0.f ? a : NEG_SLOPE * a;
                wvv = __expf(a - mx) * inv;
            }
            const int iters = (cnt2 + 1) >> 1;
            int k = 0;
            for (; k + 2 <= iters; k += 2) {
                const int e0 = slot + k * 2;
                const int e1 = e0 + 2;
                int   pA = __shfl(pv, e0);
                float wA = __shfl(wvv, e0);
                int   pB = __shfl(pv, e1);
                float wB = __shfl(wvv, e1);
                const u32x4 rA = *(const u32x4*)(A1 + (long long)pA * 256 + hl * 8);
                const u32x4 rB = *(const u32x4*)(A1 + (long long)pB * 256 + hl * 8);
                fma8s(accA, wA, rA);
                fma8s(accB, wB, rB);
            }
            if (k < iters) {
                const int e0 = slot + k * 2;
                int   pA = __shfl(pv, e0);
                float wA = __shfl(wvv, e0);
                const u32x4 rA = *(const u32x4*)(A1 + (long long)pA * 256 + hl * 8);
                fma8s(accA, wA, rA);
            }
        }

        float acc[8];
        #pragma unroll
        for (int i = 0; i < 8; ++i) acc[i] = accA[i] + accB[i];
        #pragma unroll
        for (int t2 = 0; t2 < 8; ++t2) acc[t2] += __shfl_xor(acc[t2], 32);

        if (slot == 0) {
            u32x4 pack;
            #pragma unroll
            for (int t2 = 0; t2 < 4; ++t2)
                pack[t2] = (unsigned)f2bf(acc[2 * t2]) | ((unsigned)f2bf(acc[2 * t2 + 1]) << 16);
            *(u32x4*)(z + (long long)d * 512 + seg * 256 + hl * 8) = pack;
        }
    }
}

// ---------------------------------------------------------------------------
// Layer-2 aggregation (C=64): gather xw2[et] rows; et positional (j>=mid).
// Fast path for union degree <= 64. Uniform shfls only. (round-10 validated)
// ---------------------------------------------------------------------------
__global__ __launch_bounds__(256) void aggregate2(
    const unsigned short* __restrict__ xw,   // [2][MPAD][64] bf16
    const float* __restrict__ qn,            // [2][n]
    const float* __restrict__ kn,            // [2][n]
    const int* __restrict__ row_ptr2,
    const int* __restrict__ epk,
    unsigned short* __restrict__ outb,       // [n][64] bf16 (ELU)
    float* __restrict__ outf,                // [n][64] f32
    int n)
{
    constexpr int LPE   = 8;     // 64 ch / 8 per lane
    constexpr int NSLOT = 8;

    const int wv   = ((blockIdx.x << 8) + threadIdx.x) >> 6;
    const int lane = threadIdx.x & 63;
    if (wv >= n) return;
    const int d = wv;
    const int start = row_ptr2[2 * d];
    const int mid   = row_ptr2[2 * d + 1];
    const int end   = row_ptr2[2 * d + 2];
    const int cnt = end - start;
    const int c0  = mid - start;
    const float q0 = qn[d];
    const float q1 = qn[n + d];
    const int slot = lane / LPE;
    const int hl   = lane % LPE;

    auto fma8 = [](float acc[8], float w, const u32x4& r) {
        #pragma unroll
        for (int t2 = 0; t2 < 4; ++t2) {
            unsigned dw = r[t2];
            acc[2 * t2]     = fmaf(w, __uint_as_float(dw << 16),         acc[2 * t2]);
            acc[2 * t2 + 1] = fmaf(w, __uint_as_float(dw & 0xFFFF0000u), acc[2 * t2 + 1]);
        }
    };

    float accA[8], accB[8];
    #pragma unroll
    for (int i = 0; i < 8; ++i) { accA[i] = 0.f; accB[i] = 0.f; }

    if (cnt <= 64) {
        // ---- fast path ----
        int pv = 0; float a = -INFINITY;
        if (lane < cnt) {
            pv = epk[start + lane];
            bool r1 = lane >= c0;
            a = (r1 ? q1 : q0) + kn[(r1 ? n : 0) + pv];
            a = a > 0.f ? a : NEG_SLOPE * a;
        }
        float mx = a;
        #pragma unroll
        for (int off = 32; off; off >>= 1) mx = fmaxf(mx, __shfl_xor(mx, off));
        float ev = (lane < cnt) ? __expf(a - mx) : 0.f;
        float se = ev;
        #pragma unroll
        for (int off = 32; off; off >>= 1) se += __shfl_xor(se, off);
        const float wvn = ev * (1.f / (se + 1e-16f));

        const int iters = (cnt + NSLOT - 1) / NSLOT;
        int k = 0;
        for (; k + 2 <= iters; k += 2) {
            const int e0 = slot + k * NSLOT;
            const int e1 = e0 + NSLOT;
            int   pA = __shfl(pv, e0);
            float wA = __shfl(wvn, e0);
            int   pB = __shfl(pv, e1);
            float wB = __shfl(wvn, e1);
            const long long oA = ((e0 >= c0) ? (long long)MPAD * 64 : 0) + (long long)pA * 64 + hl * 8;
            const long long oB = ((e1 >= c0) ? (long long)MPAD * 64 : 0) + (long long)pB * 64 + hl * 8;
            const u32x4 rA = *(const u32x4*)(xw + oA);
            const u32x4 rB = *(const u32x4*)(xw + oB);
            fma8(accA, wA, rA);
            fma8(accB, wB, rB);
        }
        if (k < iters) {
            const int e0 = slot + k * NSLOT;
            int   pA = __shfl(pv, e0);
            float wA = __shfl(wvn, e0);
            const long long oA = ((e0 >= c0) ? (long long)MPAD * 64 : 0) + (long long)pA * 64 + hl * 8;
            const u32x4 rA = *(const u32x4*)(xw + oA);
            fma8(accA, wA, rA);
        }
    } else {
        // ---- slow path: 3-pass chunked ----
        float mx = -INFINITY;
        for (int j = start + lane; j < end; j += 64) {
            int s = epk[j];
            bool r1 = j >= mid;
            float a = (r1 ? q1 : q0) + kn[(r1 ? n : 0) + s];
            a = a > 0.f ? a : NEG_SLOPE * a;
            mx = fmaxf(mx, a);
        }
        #pragma unroll
        for (int off = 32; off; off >>= 1) mx = fmaxf(mx, __shfl_xor(mx, off));

        float se = 0.f;
        for (int j = start + lane; j < end; j += 64) {
            int s = epk[j];
            bool r1 = j >= mid;
            float a = (r1 ? q1 : q0) + kn[(r1 ? n : 0) + s];
            a = a > 0.f ? a : NEG_SLOPE * a;
            se += __expf(a - mx);
        }
        #pragma unroll
        for (int off = 32; off; off >>= 1) se += __shfl_xor(se, off);
        const float inv = 1.f / (se + 1e-16f);

        for (int base = start; base < end; base += 64) {
            const int cnt2 = min(64, end - base);
            int pv = 0; float wvn = 0.f;
            if (lane < cnt2) {
                int j = base + lane;
                pv = epk[j];
                bool r1 = j >= mid;
                float a = (r1 ? q1 : q0) + kn[(r1 ? n : 0) + pv];
                a = a > 0.f ? a : NEG_SLOPE * a;
                wvn = __expf(a - mx) * inv;
            }
            const int iters = (cnt2 + NSLOT - 1) / NSLOT;
            int k = 0;
            for (; k + 2 <= iters; k += 2) {
                const int e0 = slot + k * NSLOT;
                const int e1 = e0 + NSLOT;
                int   pA = __shfl(pv, e0);
                float wA = __shfl(wvn, e0);
                int   pB = __shfl(pv, e1);
                float wB = __shfl(wvn, e1);
                const long long oA = ((base + e0 >= mid) ? (long long)MPAD * 64 : 0) + (long long)pA * 64 + hl * 8;
                const long long oB = ((base + e1 >= mid) ? (long long)MPAD * 64 : 0) + (long long)pB * 64 + hl * 8;
                const u32x4 rA = *(const u32x4*)(xw + oA);
                const u32x4 rB = *(const u32x4*)(xw + oB);
                fma8(accA, wA, rA);
                fma8(accB, wB, rB);
            }
            if (k < iters) {
                const int e0 = slot + k * NSLOT;
                int   pA = __shfl(pv, e0);
                float wA = __shfl(wvn, e0);
                const long long oA = ((base + e0 >= mid) ? (long long)MPAD * 64 : 0) + (long long)pA * 64 + hl * 8;
                const u32x4 rA = *(const u32x4*)(xw + oA);
                fma8(accA, wA, rA);
            }
        }
    }

    float acc[8];
    #pragma unroll
    for (int i = 0; i < 8; ++i) acc[i] = accA[i] + accB[i];
    #pragma unroll
    for (int off = LPE; off < 64; off <<= 1)
        #pragma unroll
        for (int t2 = 0; t2 < 8; ++t2) acc[t2] += __shfl_xor(acc[t2], off);

    if (slot == 0) {
        float fo[8];
        #pragma unroll
        for (int t2 = 0; t2 < 8; ++t2) fo[t2] = elu(acc[t2]);
        u32x4 pack;
        #pragma unroll
        for (int t2 = 0; t2 < 4; ++t2)
            pack[t2] = (unsigned)f2bf(fo[2 * t2]) | ((unsigned)f2bf(fo[2 * t2 + 1]) << 16);
        *(u32x4*)(outb + (long long)d * 64 + hl * 8) = pack;
        *(float4*)(outf + (long long)d * 64 + hl * 8)     = make_float4(fo[0], fo[1], fo[2], fo[3]);
        *(float4*)(outf + (long long)d * 64 + hl * 8 + 4) = make_float4(fo[4], fo[5], fo[6], fo[7]);
    }
}

// ---------------------------------------------------------------------------
extern "C" void kernel_launch(void* const* d_in, const int* in_sizes, int n_in,
                              void* d_out, int out_size, void* d_ws, size_t ws_size,
                              hipStream_t stream)
{
    const float* features = (const float*)d_in[0];
    const int*   ei       = (const int*)d_in[1];
    const int*   etype    = (const int*)d_in[2];
    const float* w1       = (const float*)d_in[3];
    const float* q1       = (const float*)d_in[4];
    const float* k1       = (const float*)d_in[5];
    const float* w2       = (const float*)d_in[6];
    const float* q2       = (const float*)d_in[7];
    const float* k2       = (const float*)d_in[8];
    const float* dW1      = (const float*)d_in[9];
    const float* db1      = (const float*)d_in[10];
    const float* dW2      = (const float*)d_in[11];
    const float* db2      = (const float*)d_in[12];

    const int n = in_sizes[0] / IN_DIM;   // 50000
    const int E = in_sizes[2];            // 800000
    const int n2 = 2 * n;
    const int* src = ei;
    const int* dst = ei + E;

    float* out_h2 = (float*)d_out;                      // [n][64]
    float* out_h3 = out_h2 + (long long)n * OUT_D;      // [n][200]

    char* wp = (char*)d_ws;
    auto carve = [&](size_t bytes) {
        char* p = wp; wp += (bytes + 255) & ~(size_t)255; return p;
    };
    unsigned short* A1   = (unsigned short*)carve((size_t)MPAD * 256 * 2);
    unsigned short* zbuf = (unsigned short*)carve((size_t)MPAD * 512 * 2);
    unsigned short* h1   = (unsigned short*)carve((size_t)MPAD * 256 * 2);
    unsigned short* xw2  = (unsigned short*)carve((size_t)2 * MPAD * 64 * 2);
    unsigned short* h2b  = (unsigned short*)carve((size_t)MPAD * 64 * 2);
    unsigned short* tdec = (unsigned short*)carve((size_t)MPAD * 256 * 2);
    unsigned short* wst  = (unsigned short*)carve((size_t)256 * 512 * 2);
    unsigned short* w2t  = (unsigned short*)carve((size_t)2 * 64 * 256 * 2);
    unsigned short* dW1t = (unsigned short*)carve((size_t)256 * 64 * 2);
    unsigned short* dW2t = (unsigned short*)carve((size_t)256 * 256 * 2);
    float* wqv    = (float*)carve((size_t)2 * 256 * 4);
    float* wkv    = (float*)carve((size_t)2 * 256 * 4);
    float* qnb1   = (float*)carve((size_t)n2 * 4);
    float* knb1   = (float*)carve((size_t)n2 * 4);
    float* qnb2   = (float*)carve((size_t)n2 * 4);
    float* knb2   = (float*)carve((size_t)n2 * 4);
    int* row_ptr2 = (int*)carve((size_t)(n2 + 1) * 4);
    int* cursor2  = (int*)carve((size_t)n2 * 4);
    int* deg2     = (int*)carve((size_t)n2 * 4);
    int* bsum     = (int*)carve((size_t)512 * 4);
    int* epk      = (int*)carve((size_t)E * 4);

    const int EB  = (E + 255) / 256;
    const int NB2 = (n2 + 255) / 256;          // 391 (scan_bsum handles <=512)
    const int MB  = (n + 127) / 128;           // 391
    const int WAVE_N = (n + 3) / 4;

    // ---- merged prep: converts + wqk + zeroing (deg2, qnb2/knb2) ----
    prep_all<<<PB_QK2, 256, 0, stream>>>(features, w1, w2, dW1, dW2, q1, k1,
                                         A1, wst, w2t, dW1t, dW2t,
                                         wqv, wkv, deg2, qnb2, knb2, n2);

    // ---- CSR build (relation-segmented) ----
    count_kernel<<<EB, 256, 0, stream>>>(dst, etype, deg2, E);
    scan_blocksum<<<NB2, 256, 0, stream>>>(deg2, bsum, n2);
    scan_bsum<<<1, 512, 0, stream>>>(bsum, NB2);
    scan_final<<<NB2, 256, 0, stream>>>(deg2, bsum, row_ptr2, cursor2, n2);
    scatter_kernel<<<EB, 256, 0, stream>>>(dst, src, etype, cursor2, epk, E);

    // ---- layer 1: qk from features, segmented z-aggregation, K=512 GEMM+ELU ----
    qk_feat<<<WAVE_N, 256, 0, stream>>>(A1, wqv, wkv, qnb1, knb1, n);
    aggregate_z<<<WAVE_N, 256, 0, stream>>>(A1, qnb1, knb1, row_ptr2, epk, zbuf, n);
    {
        dim3 g(MB, 4, 1);
        gemm_mfma<true, true, false><<<g, 256, 0, stream>>>(zbuf, wst, nullptr, h1,
                                                            nullptr, nullptr, nullptr, nullptr,
                                                            n, HID, 512, 256, 0);
    }

    // ---- layer 2 (q/k fused into GEMM epilogue; qnb2/knb2 zeroed in prep) ----
    {
        dim3 g(MB, 1, RREL);
        gemm_mfma<true, false, true><<<g, 256, 0, stream>>>(h1, w2t, nullptr, xw2,
                                                            q2, k2, qnb2, knb2,
                                                            n, OUT_D, 256, 64, (long long)MPAD * OUT_D);
    }
    aggregate2<<<WAVE_N, 256, 0, stream>>>(xw2, qnb2, knb2, row_ptr2, epk,
                                           h2b, out_h2, n);

    // ---- decoder ----
    {
        dim3 g(MB, 4, 1);
        gemm_mfma<true, false, false><<<g, 256, 0, stream>>>(h2b, dW1t, db1, tdec,
                                                             nullptr, nullptr, nullptr, nullptr,
                                                             n, HID, 64, 256, 0);
    }
    {
        dim3 g(MB, 4, 1);
        gemm_mfma<false, false, false><<<g, 256, 0, stream>>>(tdec, dW2t, db2, out_h3,
                                                              nullptr, nullptr, nullptr, nullptr,
                                                              n, IN_DIM, 256, 256, 0);
    }
}